// Round 14
// baseline (2861.600 us; speedup 1.0000x reference)
//
#include <hip/hip_runtime.h>
#include <hip/hip_bf16.h>

// LiftedStructureLoss on MI355X (gfx950)
// N=8192, D=128 fp32 embeddings; int labels (0..99); scalar fp32 out.
//
// 3 launches:
//   setup:  prep (sq, bf16 convert, log2e-prescaled; zero sum_exp/cursor/ticket)
//   pass1:  upper-triangle 128x128 tiles, 512 thr, 2-chunk global_load_lds
//           staging. Negatives: row+col sums of exp(-d) -> atomic sum_exp.
//           Positives (~1%): ballot-compacted (dist, i,j) records -> pair buf.
//   pass2:  grid-stride over pair records: relu(1+log(se_i+se_j)+d)^2 sum;
//           ticket: last block -> out = sum / npairs / 2.
//
// Scaling: ebf/sq carry log2e so exp2(-sqrt(d2s)) = exp(-d); true d =
// sqrt(d2s)*ln2. MARGIN's e^1 folds into the +1 inside pass2's log term.

typedef __attribute__((ext_vector_type(8))) short bf16x8;
typedef __attribute__((ext_vector_type(4))) float f32x4;

#if __has_builtin(__builtin_amdgcn_exp2f)
#define EXP2F __builtin_amdgcn_exp2f
#else
#define EXP2F exp2f
#endif

#define PAIR_CAP (1u << 22)   // 4M pairs (32MB); actual ~336K

__device__ __forceinline__ unsigned short f2bf(float f) {
    unsigned u = __float_as_uint(f);
    u += 0x7fffu + ((u >> 16) & 1u);   // round-to-nearest-even
    return (unsigned short)(u >> 16);
}

// 256 blocks x 256 thr: each block preps 32 rows + zeroes its sum_exp slice.
// Block 0 also zeroes cursor + ticket.
__global__ __launch_bounds__(256) void setup_kernel(
    const float* __restrict__ e, float* __restrict__ sq,
    unsigned* __restrict__ ebf, float* __restrict__ sum_exp,
    unsigned* __restrict__ cursor, unsigned* __restrict__ ticket, int N)
{
    const int tid = threadIdx.x;
    const float LOG2E = 1.44269504088896341f;
    const int lane = tid & 63, wid = tid >> 6;
    if (blockIdx.x == 0 && tid == 0) { *cursor = 0u; *ticket = 0u; }
    if (tid < 32) sum_exp[blockIdx.x * 32 + tid] = 0.f;
    const int rowbase = (blockIdx.x * 4 + wid) * 8;
    #pragma unroll
    for (int it = 0; it < 8; ++it) {
        int row = rowbase + it;
        if (row >= N) break;
        float2 v = ((const float2*)(e + (size_t)row * 128))[lane];
        v.x *= LOG2E; v.y *= LOG2E;
        float s = v.x * v.x + v.y * v.y;
        #pragma unroll
        for (int off = 1; off < 64; off <<= 1) s += __shfl_xor(s, off, 64);
        if (lane == 0) sq[row] = s;
        unsigned bits = (unsigned)f2bf(v.x) | ((unsigned)f2bf(v.y) << 16);
        ebf[(size_t)row * 64 + lane] = bits;
    }
}

// PASS 1: one 128x128 upper-triangle tile per block, 512 thr = 8 waves of
// 64x32. K=128 in 2 chunks of 64, async global_load_lds staging.
__global__ __launch_bounds__(512) void pass1_kernel(
    const unsigned short* __restrict__ ebf,
    const float* __restrict__ sq,
    const int* __restrict__ labels,
    float* __restrict__ sum_exp,       // accumulated via fp32 atomics
    uint2* __restrict__ pairs,         // (dist bits, (row<<13)|col)
    unsigned* __restrict__ paircnt,
    int N, int nCb)
{
    __shared__ __align__(16) char a_tile[128 * 128];
    __shared__ __align__(16) char b_tile[128 * 128];
    __shared__ float rowsum[128];
    __shared__ float colsum[128];

    const int tid = threadIdx.x;
    const int lane = tid & 63, wid = tid >> 6;
    const float LN2 = 0.69314718055994531f;

    // decode linear tile id -> (bi, bj), bi <= bj
    const int t = blockIdx.x;
    int bi = (int)((2.f * nCb + 1.f - __builtin_amdgcn_sqrtf(
                   (2.f * nCb + 1.f) * (2.f * nCb + 1.f) - 8.f * t)) * 0.5f);
    if (bi < 0) bi = 0;
    if (bi > nCb - 1) bi = nCb - 1;
    while (bi + 1 <= nCb - 1 && (bi + 1) * (2 * nCb - bi) / 2 <= t) ++bi;
    while (bi > 0 && bi * (2 * nCb - bi + 1) / 2 > t) --bi;
    const int bj = bi + (t - bi * (2 * nCb - bi + 1) / 2);
    const bool diag = (bi == bj);
    const int brow = bi * 128, bcol = bj * 128;

    if (tid < 128) { rowsum[tid] = 0.f; colsum[tid] = 0.f; }

    const int wm = (wid >> 2) * 64, wn = (wid & 3) * 32;
    const int lhi = lane >> 4, llo = lane & 15;
    const char* ebfB = (const char*)ebf;

    f32x4 acc[4][2];
    #pragma unroll
    for (int m = 0; m < 4; ++m)
        #pragma unroll
        for (int n = 0; n < 2; ++n)
            acc[m][n] = (f32x4){0.f, 0.f, 0.f, 0.f};

    #pragma unroll
    for (int c = 0; c < 2; ++c) {
        // async stage: 2048 16B slots, wave wid covers [wid*256, +256)
        #pragma unroll
        for (int k = 0; k < 4; ++k) {
            int s = wid * 256 + k * 64;          // wave-uniform slot base
            int tsel = s >> 10;                  // 0: a_tile, 1: b_tile
            int ls = s & 1023;
            int sl = ls + lane;                  // per-lane slot within tile
            int r = sl >> 3, j = sl & 7;
            int grow = (tsel ? bcol : brow) + r;
            const void* g = ebfB + ((size_t)grow << 8) + c * 128 + ((j ^ (r & 7)) << 4);
            char* l = (tsel ? b_tile : a_tile) + ls * 16;   // wave-uniform
            __builtin_amdgcn_global_load_lds(
                (const __attribute__((address_space(1))) unsigned*)g,
                (__attribute__((address_space(3))) unsigned*)l, 16, 0, 0);
        }
        __syncthreads();   // drains vmcnt before ds_read

        #pragma unroll
        for (int h = 0; h < 2; ++h) {
            const int cb = h * 64 + lhi * 16;
            bf16x8 af[4], bfr[2];
            #pragma unroll
            for (int m = 0; m < 4; ++m) {
                int r = wm + m * 16 + llo;
                af[m] = *(const bf16x8*)(a_tile + r * 128 + (cb ^ ((r & 7) << 4)));
            }
            #pragma unroll
            for (int n = 0; n < 2; ++n) {
                int r = wn + n * 16 + llo;
                bfr[n] = *(const bf16x8*)(b_tile + r * 128 + (cb ^ ((r & 7) << 4)));
            }
            #pragma unroll
            for (int m = 0; m < 4; ++m)
                #pragma unroll
                for (int n = 0; n < 2; ++n)
                    acc[m][n] = __builtin_amdgcn_mfma_f32_16x16x32_bf16(af[m], bfr[n], acc[m][n], 0, 0, 0);
        }
        __syncthreads();
    }

    // ---- epilogue ----
    // C/D layout: col = lane&15, row = (lane>>4)*4 + reg
    const int rowbase = brow + wm;
    float sqr[4][4]; int labr[4][4];
    #pragma unroll
    for (int m = 0; m < 4; ++m)
        #pragma unroll
        for (int r = 0; r < 4; ++r) {
            int row = rowbase + m * 16 + lhi * 4 + r;
            sqr[m][r] = sq[row];
            labr[m][r] = labels[row];
        }
    float sqc[2]; int labc[2];
    #pragma unroll
    for (int n = 0; n < 2; ++n) {
        int col = bcol + wn + n * 16 + llo;
        sqc[n] = sq[col];
        labc[n] = labels[col];
    }

    float wsum[4][4] = {};
    float csum[2] = {};
    #pragma unroll
    for (int m = 0; m < 4; ++m)
        #pragma unroll
        for (int n = 0; n < 2; ++n)
            #pragma unroll
            for (int r = 0; r < 4; ++r) {
                float g = acc[m][n][r];
                float d2 = fmaxf(fmaf(-2.f, g, sqr[m][r] + sqc[n]), 0.f);
                float dist = __builtin_amdgcn_sqrtf(d2);   // log2e * d
                bool same = (labr[m][r] == labc[n]);
                float w = same ? 0.f : EXP2F(0.f - dist);
                wsum[m][r] += w;
                csum[n] += w;

                // positive-pair emission (rare): unordered, row<col always
                int row = rowbase + m * 16 + lhi * 4 + r;
                int col = bcol + wn + n * 16 + llo;
                bool pos = same && (!diag || col > row);
                unsigned long long mask = __ballot(pos);
                if (mask) {
                    int ldr = __ffsll((unsigned long long)mask) - 1;
                    int tot = __popcll(mask);
                    unsigned long long below =
                        (lane == 0) ? 0ull : (mask << (64 - lane));
                    int rank = __popcll(below);
                    unsigned basep = 0;
                    if (lane == ldr) basep = atomicAdd(paircnt, (unsigned)tot);
                    basep = (unsigned)__shfl((int)basep, ldr, 64);
                    if (pos) {
                        unsigned idx = basep + (unsigned)rank;
                        if (idx < PAIR_CAP) {
                            uint2 rec;
                            rec.x = __float_as_uint(dist * LN2);   // true d
                            rec.y = ((unsigned)row << 13) | (unsigned)col;
                            pairs[idx] = rec;
                        }
                    }
                }
            }
    // row sums: reduce across 16 llo lanes
    #pragma unroll
    for (int m = 0; m < 4; ++m)
        #pragma unroll
        for (int r = 0; r < 4; ++r) {
            float s = wsum[m][r];
            #pragma unroll
            for (int off = 1; off < 16; off <<= 1) s += __shfl_xor(s, off, 64);
            if (llo == 0)
                atomicAdd(&rowsum[wm + m * 16 + lhi * 4 + r], s);
        }
    // col sums: reduce across the 4 lhi groups
    if (!diag) {
        #pragma unroll
        for (int n = 0; n < 2; ++n) {
            float s = csum[n];
            s += __shfl_xor(s, 16, 64);
            s += __shfl_xor(s, 32, 64);
            if (lhi == 0)
                atomicAdd(&colsum[wn + n * 16 + llo], s);
        }
    }
    __syncthreads();
    if (tid < 128) {
        unsafeAtomicAdd(&sum_exp[brow + tid], rowsum[tid]);
        if (!diag)
            unsafeAtomicAdd(&sum_exp[bcol + tid], colsum[tid]);
    }
}

// PASS 2: grid-stride over pair records. sum_exp holds sum(exp(-d)); true
// sum_exp = e * that, so log(true_i + true_j) = 1 + log(s_i + s_j).
// out = sum / npairs / 2 (unordered == ordered ratio).
__global__ __launch_bounds__(256) void pass2_kernel(
    const float* __restrict__ sum_exp,
    const uint2* __restrict__ pairs,
    const unsigned* __restrict__ paircnt,
    double* __restrict__ partial2,
    unsigned* __restrict__ ticket,
    float* __restrict__ out)
{
    __shared__ double bsum[4];
    __shared__ bool isLast;
    const int tid = threadIdx.x;
    const int lane = tid & 63, wid = tid >> 6;
    const int NB = gridDim.x;
    const unsigned np = min(*paircnt, PAIR_CAP);

    float lsum = 0.f;
    for (unsigned i = blockIdx.x * 256 + tid; i < np; i += NB * 256) {
        uint2 rec = pairs[i];
        float d = __uint_as_float(rec.x);
        int row = rec.y >> 13, col = rec.y & 8191;
        float se = sum_exp[row] + sum_exp[col];
        float L = 1.f + __logf(se) + d;
        L = fmaxf(L, 0.f);
        lsum += L * L;
    }
    #pragma unroll
    for (int off = 1; off < 64; off <<= 1) lsum += __shfl_xor(lsum, off, 64);
    if (lane == 0) bsum[wid] = (double)lsum;
    __syncthreads();
    if (tid == 0) {
        partial2[blockIdx.x] = bsum[0] + bsum[1] + bsum[2] + bsum[3];
        __threadfence();
        isLast = (atomicAdd(ticket, 1u) == (unsigned)(NB - 1));
    }
    __syncthreads();

    if (isLast) {
        __threadfence();
        double tt = (tid < NB) ? partial2[tid] : 0.0;
        #pragma unroll
        for (int off = 1; off < 64; off <<= 1) tt += __shfl_xor(tt, off, 64);
        if (lane == 0) bsum[wid] = tt;
        __syncthreads();
        if (tid == 0) {
            double s = bsum[0] + bsum[1] + bsum[2] + bsum[3];
            unsigned cc = np ? np : 1u;
            out[0] = (float)(s / (double)cc * 0.5);
        }
    }
}

extern "C" void kernel_launch(void* const* d_in, const int* in_sizes, int n_in,
                              void* d_out, int out_size, void* d_ws, size_t ws_size,
                              hipStream_t stream) {
    const float* e = (const float*)d_in[0];
    const int* labels = (const int*)d_in[1];
    const int N = in_sizes[1];                 // 8192
    const int nCb = N / 128;                   // 64
    const int nT = nCb * (nCb + 1) / 2;        // 2080
    const int nPrep = N / 32;                  // 256
    const int NB2 = 256;                       // pass2 grid

    char* ws = (char*)d_ws;
    float*    sq       = (float*)ws;
    float*    sum_exp  = (float*)(ws + 4 * (size_t)N);
    unsigned short* ebf = (unsigned short*)(ws + 8 * (size_t)N);
    char*     p        = ws + 8 * (size_t)N + 256 * (size_t)N;
    unsigned* cursor   = (unsigned*)p;
    unsigned* ticket   = (unsigned*)(p + 4);
    p += 64;
    double*   partial2 = (double*)p;   p += NB2 * 8;
    uint2*    pairs    = (uint2*)p;    // PAIR_CAP * 8 bytes (ws is ~256MB)

    setup_kernel<<<nPrep, 256, 0, stream>>>(e, sq, (unsigned*)ebf, sum_exp,
                                            cursor, ticket, N);
    pass1_kernel<<<nT, 512, 0, stream>>>(ebf, sq, labels, sum_exp,
                                         pairs, cursor, N, nCb);
    pass2_kernel<<<NB2, 256, 0, stream>>>(sum_exp, pairs, cursor,
                                          partial2, ticket, (float*)d_out);
}

// Round 15
// 80.716 us; speedup vs baseline: 35.4526x; 35.4526x over previous
//
#include <hip/hip_runtime.h>
#include <hip/hip_bf16.h>

// LiftedStructureLoss on MI355X (gfx950)
// N=8192, D=128 fp32 embeddings; int labels (0..99); scalar fp32 out.
//
// 3 launches:
//   setup:  prep (sq, bf16 convert, log2e-prescaled; zero sum_exp/cursor/ticket)
//   pass1:  upper-triangle 128x128 tiles, 512 thr, 2-chunk global_load_lds
//           staging. Negatives: row+col sums of exp(-d) -> atomic sum_exp.
//           Positives (~164/tile): staged in LDS (a_tile reuse), ONE
//           atomicAdd(paircnt) per block, coalesced flush.
//   pass2:  grid-stride over pair records: relu(1+log(se_i+se_j)+d)^2 sum;
//           ticket: last block -> out = sum / npairs / 2.
//
// Scaling: ebf/sq carry log2e so exp2(-sqrt(d2s)) = exp(-d); true d =
// sqrt(d2s)*ln2. MARGIN's e^1 folds into the +1 inside pass2's log term.

typedef __attribute__((ext_vector_type(8))) short bf16x8;
typedef __attribute__((ext_vector_type(4))) float f32x4;

#if __has_builtin(__builtin_amdgcn_exp2f)
#define EXP2F __builtin_amdgcn_exp2f
#else
#define EXP2F exp2f
#endif

#define PAIR_CAP (1u << 20)   // 1M pairs (8MB); actual ~332K unordered
#define LDS_PCAP 2048u        // per-block LDS pair staging (a_tile reuse)

__device__ __forceinline__ unsigned short f2bf(float f) {
    unsigned u = __float_as_uint(f);
    u += 0x7fffu + ((u >> 16) & 1u);   // round-to-nearest-even
    return (unsigned short)(u >> 16);
}

// 256 blocks x 256 thr: each block preps 32 rows + zeroes its sum_exp slice.
// Block 0 also zeroes cursor + ticket.
__global__ __launch_bounds__(256) void setup_kernel(
    const float* __restrict__ e, float* __restrict__ sq,
    unsigned* __restrict__ ebf, float* __restrict__ sum_exp,
    unsigned* __restrict__ cursor, unsigned* __restrict__ ticket, int N)
{
    const int tid = threadIdx.x;
    const float LOG2E = 1.44269504088896341f;
    const int lane = tid & 63, wid = tid >> 6;
    if (blockIdx.x == 0 && tid == 0) { *cursor = 0u; *ticket = 0u; }
    if (tid < 32) sum_exp[blockIdx.x * 32 + tid] = 0.f;
    const int rowbase = (blockIdx.x * 4 + wid) * 8;
    #pragma unroll
    for (int it = 0; it < 8; ++it) {
        int row = rowbase + it;
        if (row >= N) break;
        float2 v = ((const float2*)(e + (size_t)row * 128))[lane];
        v.x *= LOG2E; v.y *= LOG2E;
        float s = v.x * v.x + v.y * v.y;
        #pragma unroll
        for (int off = 1; off < 64; off <<= 1) s += __shfl_xor(s, off, 64);
        if (lane == 0) sq[row] = s;
        unsigned bits = (unsigned)f2bf(v.x) | ((unsigned)f2bf(v.y) << 16);
        ebf[(size_t)row * 64 + lane] = bits;
    }
}

// PASS 1: one 128x128 upper-triangle tile per block, 512 thr = 8 waves of
// 64x32. K=128 in 2 chunks of 64, async global_load_lds staging.
__global__ __launch_bounds__(512) void pass1_kernel(
    const unsigned short* __restrict__ ebf,
    const float* __restrict__ sq,
    const int* __restrict__ labels,
    float* __restrict__ sum_exp,       // accumulated via fp32 atomics
    uint2* __restrict__ pairs,         // (dist bits, (row<<13)|col)
    unsigned* __restrict__ paircnt,
    int N, int nCb)
{
    __shared__ __align__(16) char a_tile[128 * 128];   // staged K-chunk; reused as pairbuf
    __shared__ __align__(16) char b_tile[128 * 128];
    __shared__ float rowsum[128];
    __shared__ float colsum[128];
    __shared__ unsigned pcnt;
    __shared__ unsigned pbase;

    const int tid = threadIdx.x;
    const int lane = tid & 63, wid = tid >> 6;
    const float LN2 = 0.69314718055994531f;

    // decode linear tile id -> (bi, bj), bi <= bj
    const int t = blockIdx.x;
    int bi = (int)((2.f * nCb + 1.f - __builtin_amdgcn_sqrtf(
                   (2.f * nCb + 1.f) * (2.f * nCb + 1.f) - 8.f * t)) * 0.5f);
    if (bi < 0) bi = 0;
    if (bi > nCb - 1) bi = nCb - 1;
    while (bi + 1 <= nCb - 1 && (bi + 1) * (2 * nCb - bi) / 2 <= t) ++bi;
    while (bi > 0 && bi * (2 * nCb - bi + 1) / 2 > t) --bi;
    const int bj = bi + (t - bi * (2 * nCb - bi + 1) / 2);
    const bool diag = (bi == bj);
    const int brow = bi * 128, bcol = bj * 128;

    if (tid < 128) { rowsum[tid] = 0.f; colsum[tid] = 0.f; }

    const int wm = (wid >> 2) * 64, wn = (wid & 3) * 32;
    const int lhi = lane >> 4, llo = lane & 15;
    const char* ebfB = (const char*)ebf;

    f32x4 acc[4][2];
    #pragma unroll
    for (int m = 0; m < 4; ++m)
        #pragma unroll
        for (int n = 0; n < 2; ++n)
            acc[m][n] = (f32x4){0.f, 0.f, 0.f, 0.f};

    #pragma unroll
    for (int c = 0; c < 2; ++c) {
        // async stage: 2048 16B slots, wave wid covers [wid*256, +256)
        #pragma unroll
        for (int k = 0; k < 4; ++k) {
            int s = wid * 256 + k * 64;          // wave-uniform slot base
            int tsel = s >> 10;                  // 0: a_tile, 1: b_tile
            int ls = s & 1023;
            int sl = ls + lane;                  // per-lane slot within tile
            int r = sl >> 3, j = sl & 7;
            int grow = (tsel ? bcol : brow) + r;
            const void* g = ebfB + ((size_t)grow << 8) + c * 128 + ((j ^ (r & 7)) << 4);
            char* l = (tsel ? b_tile : a_tile) + ls * 16;   // wave-uniform
            __builtin_amdgcn_global_load_lds(
                (const __attribute__((address_space(1))) unsigned*)g,
                (__attribute__((address_space(3))) unsigned*)l, 16, 0, 0);
        }
        __syncthreads();   // drains vmcnt before ds_read

        #pragma unroll
        for (int h = 0; h < 2; ++h) {
            const int cb = h * 64 + lhi * 16;
            bf16x8 af[4], bfr[2];
            #pragma unroll
            for (int m = 0; m < 4; ++m) {
                int r = wm + m * 16 + llo;
                af[m] = *(const bf16x8*)(a_tile + r * 128 + (cb ^ ((r & 7) << 4)));
            }
            #pragma unroll
            for (int n = 0; n < 2; ++n) {
                int r = wn + n * 16 + llo;
                bfr[n] = *(const bf16x8*)(b_tile + r * 128 + (cb ^ ((r & 7) << 4)));
            }
            #pragma unroll
            for (int m = 0; m < 4; ++m)
                #pragma unroll
                for (int n = 0; n < 2; ++n)
                    acc[m][n] = __builtin_amdgcn_mfma_f32_16x16x32_bf16(af[m], bfr[n], acc[m][n], 0, 0, 0);
        }
        __syncthreads();
    }

    // a_tile is dead from here (all ds_reads drained) -> reuse as pair staging
    uint2* pairbuf = (uint2*)a_tile;
    if (tid == 0) pcnt = 0u;
    __syncthreads();

    // ---- epilogue ----
    // C/D layout: col = lane&15, row = (lane>>4)*4 + reg
    const int rowbase = brow + wm;
    float sqr[4][4]; int labr[4][4];
    #pragma unroll
    for (int m = 0; m < 4; ++m)
        #pragma unroll
        for (int r = 0; r < 4; ++r) {
            int row = rowbase + m * 16 + lhi * 4 + r;
            sqr[m][r] = sq[row];
            labr[m][r] = labels[row];
        }
    float sqc[2]; int labc[2];
    #pragma unroll
    for (int n = 0; n < 2; ++n) {
        int col = bcol + wn + n * 16 + llo;
        sqc[n] = sq[col];
        labc[n] = labels[col];
    }

    float wsum[4][4] = {};
    float csum[2] = {};
    #pragma unroll
    for (int m = 0; m < 4; ++m)
        #pragma unroll
        for (int n = 0; n < 2; ++n)
            #pragma unroll
            for (int r = 0; r < 4; ++r) {
                float g = acc[m][n][r];
                float d2 = fmaxf(fmaf(-2.f, g, sqr[m][r] + sqc[n]), 0.f);
                float dist = __builtin_amdgcn_sqrtf(d2);   // log2e * d
                bool same = (labr[m][r] == labc[n]);
                float w = same ? 0.f : EXP2F(0.f - dist);
                wsum[m][r] += w;
                csum[n] += w;

                // positive pair (rare): stage in LDS
                int row = rowbase + m * 16 + lhi * 4 + r;
                int col = bcol + wn + n * 16 + llo;
                bool pos = same && (!diag || col > row);
                if (pos) {
                    uint2 rec;
                    rec.x = __float_as_uint(dist * LN2);   // true d
                    rec.y = ((unsigned)row << 13) | (unsigned)col;
                    unsigned idx = atomicAdd(&pcnt, 1u);
                    if (idx < LDS_PCAP) {
                        pairbuf[idx] = rec;
                    } else {
                        unsigned gidx = atomicAdd(paircnt, 1u);  // overflow fallback
                        if (gidx < PAIR_CAP) pairs[gidx] = rec;
                    }
                }
            }
    // row sums: reduce across 16 llo lanes
    #pragma unroll
    for (int m = 0; m < 4; ++m)
        #pragma unroll
        for (int r = 0; r < 4; ++r) {
            float s = wsum[m][r];
            #pragma unroll
            for (int off = 1; off < 16; off <<= 1) s += __shfl_xor(s, off, 64);
            if (llo == 0)
                atomicAdd(&rowsum[wm + m * 16 + lhi * 4 + r], s);
        }
    // col sums: reduce across the 4 lhi groups
    if (!diag) {
        #pragma unroll
        for (int n = 0; n < 2; ++n) {
            float s = csum[n];
            s += __shfl_xor(s, 16, 64);
            s += __shfl_xor(s, 32, 64);
            if (lhi == 0)
                atomicAdd(&colsum[wn + n * 16 + llo], s);
        }
    }
    __syncthreads();

    // ---- flush: sum_exp atomics + one paircnt reservation per block ----
    if (tid < 128) {
        unsafeAtomicAdd(&sum_exp[brow + tid], rowsum[tid]);
        if (!diag)
            unsafeAtomicAdd(&sum_exp[bcol + tid], colsum[tid]);
    }
    unsigned cl = min(pcnt, LDS_PCAP);
    if (tid == 0) pbase = atomicAdd(paircnt, cl);
    __syncthreads();
    for (unsigned i = tid; i < cl; i += 512) {
        unsigned g = pbase + i;
        if (g < PAIR_CAP) pairs[g] = pairbuf[i];
    }
}

// PASS 2: grid-stride over pair records. sum_exp holds sum(exp(-d)); true
// sum_exp = e * that, so log(true_i + true_j) = 1 + log(s_i + s_j).
// out = sum / npairs / 2 (unordered == ordered ratio).
__global__ __launch_bounds__(256) void pass2_kernel(
    const float* __restrict__ sum_exp,
    const uint2* __restrict__ pairs,
    const unsigned* __restrict__ paircnt,
    double* __restrict__ partial2,
    unsigned* __restrict__ ticket,
    float* __restrict__ out)
{
    __shared__ double bsum[4];
    __shared__ bool isLast;
    const int tid = threadIdx.x;
    const int lane = tid & 63, wid = tid >> 6;
    const int NB = gridDim.x;
    const unsigned np = min(*paircnt, PAIR_CAP);

    float lsum = 0.f;
    for (unsigned i = blockIdx.x * 256 + tid; i < np; i += NB * 256) {
        uint2 rec = pairs[i];
        float d = __uint_as_float(rec.x);
        int row = rec.y >> 13, col = rec.y & 8191;
        float se = sum_exp[row] + sum_exp[col];
        float L = 1.f + __logf(se) + d;
        L = fmaxf(L, 0.f);
        lsum += L * L;
    }
    #pragma unroll
    for (int off = 1; off < 64; off <<= 1) lsum += __shfl_xor(lsum, off, 64);
    if (lane == 0) bsum[wid] = (double)lsum;
    __syncthreads();
    if (tid == 0) {
        partial2[blockIdx.x] = bsum[0] + bsum[1] + bsum[2] + bsum[3];
        __threadfence();
        isLast = (atomicAdd(ticket, 1u) == (unsigned)(NB - 1));
    }
    __syncthreads();

    if (isLast) {
        __threadfence();
        double tt = (tid < NB) ? partial2[tid] : 0.0;
        #pragma unroll
        for (int off = 1; off < 64; off <<= 1) tt += __shfl_xor(tt, off, 64);
        if (lane == 0) bsum[wid] = tt;
        __syncthreads();
        if (tid == 0) {
            double s = bsum[0] + bsum[1] + bsum[2] + bsum[3];
            unsigned cc = np ? np : 1u;
            out[0] = (float)(s / (double)cc * 0.5);
        }
    }
}

extern "C" void kernel_launch(void* const* d_in, const int* in_sizes, int n_in,
                              void* d_out, int out_size, void* d_ws, size_t ws_size,
                              hipStream_t stream) {
    const float* e = (const float*)d_in[0];
    const int* labels = (const int*)d_in[1];
    const int N = in_sizes[1];                 // 8192
    const int nCb = N / 128;                   // 64
    const int nT = nCb * (nCb + 1) / 2;        // 2080
    const int nPrep = N / 32;                  // 256
    const int NB2 = 256;                       // pass2 grid

    char* ws = (char*)d_ws;
    float*    sq       = (float*)ws;
    float*    sum_exp  = (float*)(ws + 4 * (size_t)N);
    unsigned short* ebf = (unsigned short*)(ws + 8 * (size_t)N);
    char*     p        = ws + 8 * (size_t)N + 256 * (size_t)N;
    unsigned* cursor   = (unsigned*)p;
    unsigned* ticket   = (unsigned*)(p + 4);
    p += 64;
    double*   partial2 = (double*)p;   p += NB2 * 8;
    uint2*    pairs    = (uint2*)p;    // PAIR_CAP * 8 bytes

    setup_kernel<<<nPrep, 256, 0, stream>>>(e, sq, (unsigned*)ebf, sum_exp,
                                            cursor, ticket, N);
    pass1_kernel<<<nT, 512, 0, stream>>>(ebf, sq, labels, sum_exp,
                                         pairs, cursor, N, nCb);
    pass2_kernel<<<NB2, 256, 0, stream>>>(sum_exp, pairs, cursor,
                                          partial2, ticket, (float*)d_out);
}